// Round 4
// baseline (974.291 us; speedup 1.0000x reference)
//
#include <hip/hip_runtime.h>

// Problem: out = u2 + trilinear(u1, grid + u2); B=2, D=H=W=160, C=3, fp32.
constexpr int Bn = 2;
constexpr int Dn = 160;
constexpr int Hn = 160;
constexpr int Wn = 160;
constexpr int NV  = Bn * Dn * Hn * Wn;         // 8,192,000 voxels
constexpr int VOL = Dn * Hn * Wn;              // 4,096,000 voxels / batch

constexpr int TPB  = 256;
constexpr int NBLK = NV / TPB;                 // 32000 blocks (exact)
constexpr int NXCD = 8;
constexpr int CHUNK = NBLK / NXCD;             // 4000 blocks per XCD chunk

typedef float f32x4 __attribute__((ext_vector_type(4)));

// warp1 buffer byte size and the max safe 48B-window start
constexpr unsigned W1_BYTES = (unsigned)NV * 12u;      // 98,304,000
constexpr unsigned GEND     = W1_BYTES - 48u;

// Select r[0..5] = vv[k..k+5] from a 48B window, k in 0..6, all indices
// compile-time (unrolled cndmask chains — no scratch, rule #20 safe).
__device__ __forceinline__ void extract6(const f32x4& A, const f32x4& B,
                                         const f32x4& C, unsigned k,
                                         float r[6]) {
    float vv[13] = {A.x, A.y, A.z, A.w,
                    B.x, B.y, B.z, B.w,
                    C.x, C.y, C.z, C.w, 0.0f};
    bool b4 = (k & 4u) != 0u;
    bool b2 = (k & 2u) != 0u;
    bool b1 = (k & 1u) != 0u;
    float s4[9];
#pragma unroll
    for (int i = 0; i < 9; ++i) s4[i] = b4 ? vv[i + 4] : vv[i];
    float s2[7];
#pragma unroll
    for (int i = 0; i < 7; ++i) s2[i] = b2 ? s4[i + 2] : s4[i];
#pragma unroll
    for (int i = 0; i < 6; ++i) r[i] = b1 ? s2[i + 1] : s2[i];
}

__global__ __launch_bounds__(TPB) void compose_transform_kernel(
    const float* __restrict__ warp1,
    const float* __restrict__ warp2,
    float* __restrict__ out) {

    // XCD-chunked swizzle (proven: FETCH 389->100 MB). Bijective since
    // NBLK % NXCD == 0.
    int bid = blockIdx.x;
    int swz = (bid & (NXCD - 1)) * CHUNK + (bid >> 3);

    int idx = swz * TPB + (int)threadIdx.x;    // voxel id over B*D*H*W

    // decode (b, d, h, w)
    int w  = idx % Wn;
    int t  = idx / Wn;
    int h  = t % Hn;
    t      = t / Hn;
    int d  = t % Dn;
    int b  = t / Dn;

    int base3 = idx * 3;
    // streaming read — nontemporal to keep L2/L3 for the warp1 gathers
    float u2x = __builtin_nontemporal_load(warp2 + base3 + 0);
    float u2y = __builtin_nontemporal_load(warp2 + base3 + 1);
    float u2z = __builtin_nontemporal_load(warp2 + base3 + 2);

    // loc = grid + u2, clipped to [0, size-1]
    float lx = fminf(fmaxf((float)d + u2x, 0.0f), (float)(Dn - 1));
    float ly = fminf(fmaxf((float)h + u2y, 0.0f), (float)(Hn - 1));
    float lz = fminf(fmaxf((float)w + u2z, 0.0f), (float)(Wn - 1));

    // Border-remapped bases: ixb in [0, size-2]; the clamped duplicate corner
    // gets full weight — matches i1=min(i0+1,..) reference semantics exactly.
    int ixb = min((int)floorf(lx), Dn - 2);
    int iyb = min((int)floorf(ly), Hn - 2);
    int izb = min((int)floorf(lz), Wn - 2);

    float wx1 = lx - (float)ixb, wx0 = 1.0f - wx1;
    float wy1 = ly - (float)iyb, wy0 = 1.0f - wy1;
    float wz1 = lz - (float)izb, wz0 = 1.0f - wz1;

    // Row start byte offsets into the warp1 buffer (fold batch in).
    unsigned vbase = (unsigned)b * (unsigned)(VOL * 12);
    unsigned R00 = vbase + (unsigned)(((ixb * Hn + iyb) * Wn + izb) * 12);
    unsigned R01 = R00 + (unsigned)(Wn * 12);
    unsigned R10 = R00 + (unsigned)(Hn * Wn * 12);
    unsigned R11 = R10 + (unsigned)(Wn * 12);

    // Aligned-down 48B windows (3 x dwordx4 each) + end clamp.
    unsigned B00 = min(R00 & ~15u, GEND);
    unsigned B01 = min(R01 & ~15u, GEND);
    unsigned B10 = min(R10 & ~15u, GEND);
    unsigned B11 = min(R11 & ~15u, GEND);

    const char* w1b = reinterpret_cast<const char*>(warp1);
    const f32x4* p00 = reinterpret_cast<const f32x4*>(w1b + B00);
    const f32x4* p01 = reinterpret_cast<const f32x4*>(w1b + B01);
    const f32x4* p10 = reinterpret_cast<const f32x4*>(w1b + B10);
    const f32x4* p11 = reinterpret_cast<const f32x4*>(w1b + B11);

    // Issue all 12 vector loads before any use — maximize loads in flight.
    f32x4 A00 = p00[0], Bv00 = p00[1], C00 = p00[2];
    f32x4 A01 = p01[0], Bv01 = p01[1], C01 = p01[2];
    f32x4 A10 = p10[0], Bv10 = p10[1], C10 = p10[2];
    f32x4 A11 = p11[0], Bv11 = p11[1], C11 = p11[2];

    unsigned k00 = (R00 - B00) >> 2;
    unsigned k01 = (R01 - B01) >> 2;
    unsigned k10 = (R10 - B10) >> 2;
    unsigned k11 = (R11 - B11) >> 2;

    float w00 = wx0 * wy0;
    float w01 = wx0 * wy1;
    float w10 = wx1 * wy0;
    float w11 = wx1 * wy1;

    float r[6];
    float rx, ry, rz;
    float accx, accy, accz;

    extract6(A00, Bv00, C00, k00, r);
    rx = fmaf(wz1, r[3], wz0 * r[0]);
    ry = fmaf(wz1, r[4], wz0 * r[1]);
    rz = fmaf(wz1, r[5], wz0 * r[2]);
    accx = w00 * rx; accy = w00 * ry; accz = w00 * rz;

    extract6(A01, Bv01, C01, k01, r);
    rx = fmaf(wz1, r[3], wz0 * r[0]);
    ry = fmaf(wz1, r[4], wz0 * r[1]);
    rz = fmaf(wz1, r[5], wz0 * r[2]);
    accx = fmaf(w01, rx, accx); accy = fmaf(w01, ry, accy); accz = fmaf(w01, rz, accz);

    extract6(A10, Bv10, C10, k10, r);
    rx = fmaf(wz1, r[3], wz0 * r[0]);
    ry = fmaf(wz1, r[4], wz0 * r[1]);
    rz = fmaf(wz1, r[5], wz0 * r[2]);
    accx = fmaf(w10, rx, accx); accy = fmaf(w10, ry, accy); accz = fmaf(w10, rz, accz);

    extract6(A11, Bv11, C11, k11, r);
    rx = fmaf(wz1, r[3], wz0 * r[0]);
    ry = fmaf(wz1, r[4], wz0 * r[1]);
    rz = fmaf(wz1, r[5], wz0 * r[2]);
    accx = fmaf(w11, rx, accx); accy = fmaf(w11, ry, accy); accz = fmaf(w11, rz, accz);

    // streaming write — scalar nontemporal (WRITE_SIZE exactly 96000 KB)
    __builtin_nontemporal_store(u2x + accx, out + base3 + 0);
    __builtin_nontemporal_store(u2y + accy, out + base3 + 1);
    __builtin_nontemporal_store(u2z + accz, out + base3 + 2);
}

extern "C" void kernel_launch(void* const* d_in, const int* in_sizes, int n_in,
                              void* d_out, int out_size, void* d_ws, size_t ws_size,
                              hipStream_t stream) {
    const float* warp1 = (const float*)d_in[0];
    const float* warp2 = (const float*)d_in[1];
    float* out = (float*)d_out;

    compose_transform_kernel<<<NBLK, TPB, 0, stream>>>(warp1, warp2, out);
}

// Round 5
// 362.692 us; speedup vs baseline: 2.6863x; 2.6863x over previous
//
#include <hip/hip_runtime.h>

// Problem: out = u2 + trilinear(u1, grid + u2); B=2, D=H=W=160, C=3, fp32.
constexpr int Bn = 2;
constexpr int Dn = 160;
constexpr int Hn = 160;
constexpr int Wn = 160;
constexpr int NV  = Bn * Dn * Hn * Wn;         // 8,192,000 voxels
constexpr int VOL = Dn * Hn * Wn;              // 4,096,000 voxels / batch

constexpr int TPB  = 256;
constexpr int NBLK = NV / TPB;                 // 32000 blocks (exact)
constexpr int NXCD = 8;
constexpr int CHUNK = NBLK / NXCD;             // 4000 blocks per XCD chunk

typedef float f32x4 __attribute__((ext_vector_type(4)));
typedef float f32x2 __attribute__((ext_vector_type(2)));

// Packed wrappers: alignment 1 -> clang emits the load with the real (4B)
// alignment; gfx950 global memory supports unaligned vector access, so the
// backend emits a single global_load_dwordx4 / dwordx2. No selection logic,
// no arrays -> nothing for promote-alloca to lower to LDS/scratch (R4 bug).
struct __attribute__((packed)) v4p { f32x4 v; };
struct __attribute__((packed)) v2p { f32x2 v; };

__global__ __launch_bounds__(TPB) void compose_transform_kernel(
    const float* __restrict__ warp1,
    const float* __restrict__ warp2,
    float* __restrict__ out) {

    // XCD-chunked swizzle (proven: FETCH 389->100 MB). Bijective since
    // NBLK % NXCD == 0.
    int bid = blockIdx.x;
    int swz = (bid & (NXCD - 1)) * CHUNK + (bid >> 3);

    int idx = swz * TPB + (int)threadIdx.x;    // voxel id over B*D*H*W

    // decode (b, d, h, w)
    int w  = idx % Wn;
    int t  = idx / Wn;
    int h  = t % Hn;
    t      = t / Hn;
    int d  = t % Dn;
    int b  = t / Dn;

    int base3 = idx * 3;
    // streaming read — nontemporal to keep L2/L3 for the warp1 gathers
    float u2x = __builtin_nontemporal_load(warp2 + base3 + 0);
    float u2y = __builtin_nontemporal_load(warp2 + base3 + 1);
    float u2z = __builtin_nontemporal_load(warp2 + base3 + 2);

    // loc = grid + u2, clipped to [0, size-1]
    float lx = fminf(fmaxf((float)d + u2x, 0.0f), (float)(Dn - 1));
    float ly = fminf(fmaxf((float)h + u2y, 0.0f), (float)(Hn - 1));
    float lz = fminf(fmaxf((float)w + u2z, 0.0f), (float)(Wn - 1));

    // Border-remapped bases: ixb in [0, size-2]; the clamped duplicate corner
    // gets full weight — matches i1=min(i0+1,..) reference semantics exactly.
    int ixb = min((int)floorf(lx), Dn - 2);
    int iyb = min((int)floorf(ly), Hn - 2);
    int izb = min((int)floorf(lz), Wn - 2);

    float wx1 = lx - (float)ixb, wx0 = 1.0f - wx1;
    float wy1 = ly - (float)iyb, wy0 = 1.0f - wy1;
    float wz1 = lz - (float)izb, wz0 = 1.0f - wz1;

    const float* __restrict__ u1 = warp1 + b * (VOL * 3);

    // 4 (x,y) rows; each row = 6 contiguous floats [c0x c0y c0z c1x c1y c1z],
    // loaded as one unaligned dwordx4 + one dwordx2.
    const float* p00 = u1 + ((ixb * Hn + iyb) * Wn + izb) * 3;
    const float* p01 = p00 + Wn * 3;           // iyb+1
    const float* p10 = p00 + Hn * Wn * 3;      // ixb+1
    const float* p11 = p10 + Wn * 3;           // ixb+1, iyb+1

    // Issue all 8 gather loads before any use — maximize loads in flight.
    f32x4 a00 = reinterpret_cast<const v4p*>(p00)->v;
    f32x2 b00 = reinterpret_cast<const v2p*>(p00 + 4)->v;
    f32x4 a01 = reinterpret_cast<const v4p*>(p01)->v;
    f32x2 b01 = reinterpret_cast<const v2p*>(p01 + 4)->v;
    f32x4 a10 = reinterpret_cast<const v4p*>(p10)->v;
    f32x2 b10 = reinterpret_cast<const v2p*>(p10 + 4)->v;
    f32x4 a11 = reinterpret_cast<const v4p*>(p11)->v;
    f32x2 b11 = reinterpret_cast<const v2p*>(p11 + 4)->v;

    float w00 = wx0 * wy0;
    float w01 = wx0 * wy1;
    float w10 = wx1 * wy0;
    float w11 = wx1 * wy1;

    // Per row: wz0 * c0 + wz1 * c1, then weighted by wxy.
    float rx, ry, rz;
    float accx, accy, accz;

    rx = fmaf(wz1, a00.w, wz0 * a00.x);
    ry = fmaf(wz1, b00.x, wz0 * a00.y);
    rz = fmaf(wz1, b00.y, wz0 * a00.z);
    accx = w00 * rx; accy = w00 * ry; accz = w00 * rz;

    rx = fmaf(wz1, a01.w, wz0 * a01.x);
    ry = fmaf(wz1, b01.x, wz0 * a01.y);
    rz = fmaf(wz1, b01.y, wz0 * a01.z);
    accx = fmaf(w01, rx, accx); accy = fmaf(w01, ry, accy); accz = fmaf(w01, rz, accz);

    rx = fmaf(wz1, a10.w, wz0 * a10.x);
    ry = fmaf(wz1, b10.x, wz0 * a10.y);
    rz = fmaf(wz1, b10.y, wz0 * a10.z);
    accx = fmaf(w10, rx, accx); accy = fmaf(w10, ry, accy); accz = fmaf(w10, rz, accz);

    rx = fmaf(wz1, a11.w, wz0 * a11.x);
    ry = fmaf(wz1, b11.x, wz0 * a11.y);
    rz = fmaf(wz1, b11.y, wz0 * a11.z);
    accx = fmaf(w11, rx, accx); accy = fmaf(w11, ry, accy); accz = fmaf(w11, rz, accz);

    // streaming write — scalar nontemporal (WRITE_SIZE exactly 96000 KB)
    __builtin_nontemporal_store(u2x + accx, out + base3 + 0);
    __builtin_nontemporal_store(u2y + accy, out + base3 + 1);
    __builtin_nontemporal_store(u2z + accz, out + base3 + 2);
}

extern "C" void kernel_launch(void* const* d_in, const int* in_sizes, int n_in,
                              void* d_out, int out_size, void* d_ws, size_t ws_size,
                              hipStream_t stream) {
    const float* warp1 = (const float*)d_in[0];
    const float* warp2 = (const float*)d_in[1];
    float* out = (float*)d_out;

    compose_transform_kernel<<<NBLK, TPB, 0, stream>>>(warp1, warp2, out);
}